// Round 1
// 137.124 us; speedup vs baseline: 1.0351x; 1.0351x over previous
//
#include <hip/hip_runtime.h>
#include <hip/hip_bf16.h>
#include <stdint.h>

typedef unsigned short u16;
typedef unsigned int u32;
typedef __attribute__((ext_vector_type(8))) short short8;
typedef __attribute__((ext_vector_type(4))) float float4v;

#define CH 128
#define OO 128
#define KD 1152      // 9*128
#define MPIX 32768   // 8*64*64

__device__ __forceinline__ u16 f2bf(float v) {
    __hip_bfloat16 h = __float2bfloat16(v);
    return *reinterpret_cast<u16*>(&h);
}

__device__ __forceinline__ float bf_lo(u32 u) {      // low bf16 of pair -> f32 (exact)
    u32 t = u << 16;
    return __builtin_bit_cast(float, t);
}
__device__ __forceinline__ float bf_hi(u32 u) {      // high bf16 of pair -> f32 (exact)
    u32 t = u & 0xffff0000u;
    return __builtin_bit_cast(float, t);
}
__device__ __forceinline__ u32 pack_bf16(float lo, float hi) {  // round-to-nearest (ties away)
    u32 ul = __builtin_bit_cast(u32, lo);
    u32 uh = __builtin_bit_cast(u32, hi);
    return ((ul + 0x8000u) >> 16) | ((uh + 0x8000u) & 0xffff0000u);
}

// ---------------- transpose x (B,C,H,W) f32 -> xt (B,H,W,C) bf16 ----------------
__global__ __launch_bounds__(256) void transpose_kernel(const float* __restrict__ x,
                                                        __hip_bfloat16* __restrict__ xt) {
    __shared__ float st[64][65];
    int tid = threadIdx.x;
    int bh = blockIdx.x;              // b*64 + h
    int b = bh >> 6;
    int h = bh & 63;
    const float* xb = x + ((size_t)b * CH) * 4096 + (size_t)h * 64;
    __hip_bfloat16* xo = xt + ((size_t)bh << 6) * CH;
    for (int cc0 = 0; cc0 < 128; cc0 += 64) {
        #pragma unroll
        for (int step = 0; step < 16; ++step) {
            int cl = (tid >> 6) + step * 4;
            int w = tid & 63;
            st[cl][w] = xb[(size_t)(cc0 + cl) * 4096 + w];
        }
        __syncthreads();
        #pragma unroll
        for (int step = 0; step < 16; ++step) {
            int w = (tid >> 6) + step * 4;
            int cl = tid & 63;
            xo[(size_t)w * CH + cc0 + cl] = __float2bfloat16(st[cl][w]);
        }
        __syncthreads();
    }
}

// ---------------- offset conv: only the 6 needed channels, 4-way c-split ----------------
__global__ __launch_bounds__(256) void offset_conv_kernel(const float* __restrict__ x,
                                                          const float* __restrict__ w_off,
                                                          float* __restrict__ partial) {
    int tid = threadIdx.x;
    int m = blockIdx.x * 256 + tid;
    int chunk = blockIdx.y;           // 0..3, 32 channels each
    int b = m >> 12;
    int hw = m & 4095;
    int h = hw >> 6;
    int w = hw & 63;
    float acc[6] = {0.f, 0.f, 0.f, 0.f, 0.f, 0.f};
    int c0 = chunk * 32;
    for (int c = c0; c < c0 + 32; ++c) {
        const float* xc = x + ((size_t)(b * CH + c) << 12);
        float xv[9];
        #pragma unroll
        for (int dy = 0; dy < 3; ++dy) {
            int yy = h + dy - 1;
            bool vy = (unsigned)yy < 64u;
            #pragma unroll
            for (int dx = 0; dx < 3; ++dx) {
                int xx = w + dx - 1;
                bool vv = vy && ((unsigned)xx < 64u);
                xv[dy * 3 + dx] = vv ? xc[yy * 64 + xx] : 0.f;
            }
        }
        const float* wb = w_off + (size_t)c * 9;
        #pragma unroll
        for (int s = 0; s < 6; ++s) {
            int chn = (s < 3) ? s * 6 : (s - 3) * 2 + 1;
            const float* wp = wb + (size_t)chn * (CH * 9);
            float a = acc[s];
            #pragma unroll
            for (int t = 0; t < 9; ++t) a = fmaf(xv[t], wp[t], a);
            acc[s] = a;
        }
    }
    float* po = partial + ((size_t)(chunk << 15) + m) * 6;
    #pragma unroll
    for (int s = 0; s < 6; ++s) po[s] = acc[s];
}

// ---------------- reorder w_main (O,C,3,3) f32 -> Wb[o][k*128+c] bf16 ----------------
__global__ __launch_bounds__(256) void wreorder_kernel(const float* __restrict__ w_main,
                                                       u16* __restrict__ Wb) {
    int idx = blockIdx.x * 256 + threadIdx.x;
    if (idx >= OO * KD) return;
    int o = idx / KD;
    int r = idx - o * KD;
    int k = r >> 7;
    int c = r & 127;
    Wb[idx] = f2bf(w_main[(size_t)o * KD + c * 9 + k]);
}

// ---------------- fused deformable-sample + GEMM ----------------
// One block = 64 pixels (one image row) x all 128 outputs. 4 waves.
// K-dim = 9 taps x 128 channels, stepped 32 at a time (36 steps), with a
// 1-deep register prefetch of both the bilinear gather loads (B) and the
// weight tile (A) so L2 latency hides under the MFMA cluster.
__global__ __launch_bounds__(256) void fused_gemm_kernel(const __hip_bfloat16* __restrict__ xt,
                                                         const float* __restrict__ partial,
                                                         const float* __restrict__ b_off,
                                                         const u16* __restrict__ Wb,
                                                         const float* __restrict__ b_main,
                                                         float* __restrict__ out) {
    __shared__ float offs[64][6];
    __shared__ __align__(16) float4v twt[64][9];   // bilinear weights per (pix, tap)
    __shared__ __align__(16) int4 tbs[64][9];      // corner base offsets (u32-pair units)
    __shared__ __align__(16) u16 lA[128 * 32];     // weight tile: o x 32 K-cols
    __shared__ __align__(16) u16 lB[64 * 32];      // sample tile: pix x 32 K-cols

    int tid = threadIdx.x;
    int m0 = blockIdx.x * 64;         // 64 consecutive pixels = one row of one image
    int b = m0 >> 12;
    int h = (m0 & 4095) >> 6;

    // -- prologue 1: gather offsets (6 per pixel) --
    for (int idx = tid; idx < 64 * 6; idx += 256) {
        int pix = idx / 6, s = idx % 6;
        int m = m0 + pix;
        int chn = (s < 3) ? s * 6 : (s - 3) * 2 + 1;
        float v = b_off[chn];
        #pragma unroll
        for (int q = 0; q < 4; ++q) v += partial[((size_t)(q << 15) + m) * 6 + s];
        offs[pix][s] = v;
    }
    __syncthreads();

    // -- prologue 2: per-(pix,tap) bilinear weights + corner bases --
    for (int idx = tid; idx < 64 * 9; idx += 256) {
        int pix = idx / 9, k = idx % 9;
        int i = k / 3, j = k - i * 3;
        float ox = offs[pix][0];
        if (i >= 1) ox += offs[pix][1];
        if (i >= 2) ox += offs[pix][2];
        float oy = offs[pix][3];
        if (j >= 1) oy += offs[pix][4];
        if (j >= 2) oy += offs[pix][5];
        const float step = 2.0f / 63.0f;
        float bxn = -1.0f + pix * step;
        float byn = -1.0f + h * step;
        float gx = fmaf(bxn + ox, 32.0f, 31.5f);
        float gy = fmaf(byn + oy, 32.0f, 31.5f);
        float x0f = floorf(gx), y0f = floorf(gy);
        float wx = gx - x0f, wy = gy - y0f;
        int ix0 = (int)x0f, iy0 = (int)y0f;
        int ix1 = ix0 + 1, iy1 = iy0 + 1;
        float fx0 = ((unsigned)ix0 < 64u) ? 1.f : 0.f;
        float fx1 = ((unsigned)ix1 < 64u) ? 1.f : 0.f;
        float fy0 = ((unsigned)iy0 < 64u) ? 1.f : 0.f;
        float fy1 = ((unsigned)iy1 < 64u) ? 1.f : 0.f;
        float4v wv;
        wv[0] = (1.f - wy) * (1.f - wx) * fy0 * fx0;
        wv[1] = (1.f - wy) * wx * fy0 * fx1;
        wv[2] = wy * (1.f - wx) * fy1 * fx0;
        wv[3] = wy * wx * fy1 * fx1;
        int cx0 = min(max(ix0, 0), 63), cx1 = min(max(ix1, 0), 63);
        int cy0 = min(max(iy0, 0), 63), cy1 = min(max(iy1, 0), 63);
        twt[pix][k] = wv;
        tbs[pix][k] = make_int4((cy0 * 64 + cx0) * 64, (cy0 * 64 + cx1) * 64,
                                (cy1 * 64 + cx0) * 64, (cy1 * 64 + cx1) * 64);
    }
    __syncthreads();

    // -- main loop setup --
    int wave = tid >> 6, lane = tid & 63;
    int wo = wave & 1;                // o half (64 rows each)
    int wp = wave >> 1;               // pixel half (32 each)
    int mrow = lane & 15;
    int q8 = (lane >> 4) * 8;

    int pix = tid >> 2;               // 0..63: sample-staging pixel
    int cg = (tid & 3) * 8;           // channel-group base within 32-col step
    const u32* xb = (const u32*)(xt + (((size_t)b << 12) * (size_t)CH));  // bf16 pairs
    const u16* abase = Wb + (size_t)(tid >> 2) * KD + (tid & 3) * 8;      // A staging
    int asto = (tid >> 2) * 32 + (tid & 3) * 8;                           // lA dest (u16)
    int bsto = pix * 32 + cg;

    float4v acc[4][2];
    #pragma unroll
    for (int sm = 0; sm < 4; ++sm)
        #pragma unroll
        for (int sn = 0; sn < 2; ++sn)
            acc[sm][sn] = (float4v){0.f, 0.f, 0.f, 0.f};

    float4v wv;
    int4 bv;
    uint4 u00, u01, u10, u11, a0, a1;

    auto issue = [&](int kk) {
        if ((kk & 3) == 0) {
            int k = kk >> 2;
            wv = twt[pix][k];
            bv = tbs[pix][k];
        }
        const u32* xc = xb + ((((kk & 3) << 5) + cg) >> 1);
        u00 = *(const uint4*)(xc + bv.x);
        u01 = *(const uint4*)(xc + bv.y);
        u10 = *(const uint4*)(xc + bv.z);
        u11 = *(const uint4*)(xc + bv.w);
        const u16* ap = abase + kk * 32;
        a0 = *(const uint4*)ap;
        a1 = *(const uint4*)(ap + (size_t)64 * KD);
    };

    issue(0);

    for (int kk = 0; kk < 36; ++kk) {
        // write phase: regs -> LDS
        *(uint4*)&lA[asto] = a0;
        *(uint4*)&lA[asto + 64 * 32] = a1;
        {
            const u32* p00 = (const u32*)&u00;
            const u32* p01 = (const u32*)&u01;
            const u32* p10 = (const u32*)&u10;
            const u32* p11 = (const u32*)&u11;
            u32 outp[4];
            #pragma unroll
            for (int q = 0; q < 4; ++q) {
                float lo = wv[0] * bf_lo(p00[q]);
                lo = fmaf(wv[1], bf_lo(p01[q]), lo);
                lo = fmaf(wv[2], bf_lo(p10[q]), lo);
                lo = fmaf(wv[3], bf_lo(p11[q]), lo);
                float hi = wv[0] * bf_hi(p00[q]);
                hi = fmaf(wv[1], bf_hi(p01[q]), hi);
                hi = fmaf(wv[2], bf_hi(p10[q]), hi);
                hi = fmaf(wv[3], bf_hi(p11[q]), hi);
                outp[q] = pack_bf16(lo, hi);
            }
            *(uint4*)&lB[bsto] = *(const uint4*)outp;
        }
        __syncthreads();

        if (kk < 35) issue(kk + 1);   // prefetch next step; latency hides under MFMA

        short8 af[4], bfv[2];
        #pragma unroll
        for (int s = 0; s < 4; ++s)
            af[s] = *(const short8*)&lA[(wo * 64 + s * 16 + mrow) * 32 + q8];
        #pragma unroll
        for (int s = 0; s < 2; ++s)
            bfv[s] = *(const short8*)&lB[(wp * 32 + s * 16 + mrow) * 32 + q8];
        #pragma unroll
        for (int sm = 0; sm < 4; ++sm)
            #pragma unroll
            for (int sn = 0; sn < 2; ++sn)
                acc[sm][sn] = __builtin_amdgcn_mfma_f32_16x16x32_bf16(af[sm], bfv[sn],
                                                                     acc[sm][sn], 0, 0, 0);
        __syncthreads();
    }

    // epilogue: C/D layout col=lane&15 (pixel), row=(lane>>4)*4+r (o)
    #pragma unroll
    for (int sm = 0; sm < 4; ++sm) {
        int o = wo * 64 + sm * 16 + (lane >> 4) * 4;
        #pragma unroll
        for (int sn = 0; sn < 2; ++sn) {
            int pcol = m0 + wp * 32 + sn * 16 + mrow;
            int rem = pcol & 4095;
            float* op = out + (((size_t)b * OO) << 12) + rem;
            #pragma unroll
            for (int r = 0; r < 4; ++r)
                op[(size_t)(o + r) << 12] = acc[sm][sn][r] + b_main[o + r];
        }
    }
}

extern "C" void kernel_launch(void* const* d_in, const int* in_sizes, int n_in,
                              void* d_out, int out_size, void* d_ws, size_t ws_size,
                              hipStream_t stream) {
    const float* x      = (const float*)d_in[0];
    const float* w_off  = (const float*)d_in[1];
    const float* b_off  = (const float*)d_in[2];
    const float* w_main = (const float*)d_in[3];
    const float* b_main = (const float*)d_in[4];
    float* out = (float*)d_out;

    char* ws = (char*)d_ws;
    __hip_bfloat16* xt = (__hip_bfloat16*)ws;                         // 8 MB
    float* partial = (float*)(ws + 8388608);                          // 3 MB
    u16* Wb   = (u16*)(ws + 8388608 + 3145728);                       // 288 KB

    transpose_kernel<<<512, 256, 0, stream>>>(x, xt);
    offset_conv_kernel<<<dim3(128, 4), 256, 0, stream>>>(x, w_off, partial);
    wreorder_kernel<<<576, 256, 0, stream>>>(w_main, Wb);
    fused_gemm_kernel<<<MPIX / 64, 256, 0, stream>>>(xt, partial, b_off, Wb, b_main, out);
}

// Round 2
// 134.823 us; speedup vs baseline: 1.0528x; 1.0171x over previous
//
#include <hip/hip_runtime.h>
#include <hip/hip_bf16.h>
#include <stdint.h>

typedef unsigned short u16;
typedef unsigned int u32;
typedef __attribute__((ext_vector_type(8))) short short8;
typedef __attribute__((ext_vector_type(4))) float float4v;
typedef __attribute__((ext_vector_type(2))) float float2v;

#define CH 128
#define OO 128
#define KD 1152      // 9*128
#define MPIX 32768   // 8*64*64

__device__ __forceinline__ u16 f2bf(float v) {
    __hip_bfloat16 h = __float2bfloat16(v);
    return *reinterpret_cast<u16*>(&h);
}

__device__ __forceinline__ float bf_lo(u32 u) {      // low bf16 of pair -> f32 (exact)
    u32 t = u << 16;
    return __builtin_bit_cast(float, t);
}
__device__ __forceinline__ float bf_hi(u32 u) {      // high bf16 of pair -> f32 (exact)
    u32 t = u & 0xffff0000u;
    return __builtin_bit_cast(float, t);
}
__device__ __forceinline__ float2v unpk(u32 u) {
    float2v r;
    r.x = bf_lo(u);
    r.y = bf_hi(u);
    return r;
}
__device__ __forceinline__ u32 pack_bf16(float lo, float hi) {  // round-to-nearest (ties away)
    u32 ul = __builtin_bit_cast(u32, lo);
    u32 uh = __builtin_bit_cast(u32, hi);
    return ((ul + 0x8000u) >> 16) | ((uh + 0x8000u) & 0xffff0000u);
}

// ---------------- transpose x (B,C,H,W) f32 -> xt (B,H,W,C) bf16 ----------------
__global__ __launch_bounds__(256) void transpose_kernel(const float* __restrict__ x,
                                                        __hip_bfloat16* __restrict__ xt) {
    __shared__ float st[64][65];
    int tid = threadIdx.x;
    int bh = blockIdx.x;              // b*64 + h
    int b = bh >> 6;
    int h = bh & 63;
    const float* xb = x + ((size_t)b * CH) * 4096 + (size_t)h * 64;
    __hip_bfloat16* xo = xt + ((size_t)bh << 6) * CH;
    for (int cc0 = 0; cc0 < 128; cc0 += 64) {
        #pragma unroll
        for (int step = 0; step < 16; ++step) {
            int cl = (tid >> 6) + step * 4;
            int w = tid & 63;
            st[cl][w] = xb[(size_t)(cc0 + cl) * 4096 + w];
        }
        __syncthreads();
        #pragma unroll
        for (int step = 0; step < 16; ++step) {
            int w = (tid >> 6) + step * 4;
            int cl = tid & 63;
            xo[(size_t)w * CH + cc0 + cl] = __float2bfloat16(st[cl][w]);
        }
        __syncthreads();
    }
}

// ---------------- offset conv: only the 6 needed channels, 4-way c-split ----------------
__global__ __launch_bounds__(256) void offset_conv_kernel(const float* __restrict__ x,
                                                          const float* __restrict__ w_off,
                                                          float* __restrict__ partial) {
    int tid = threadIdx.x;
    int m = blockIdx.x * 256 + tid;
    int chunk = blockIdx.y;           // 0..3, 32 channels each
    int b = m >> 12;
    int hw = m & 4095;
    int h = hw >> 6;
    int w = hw & 63;
    float acc[6] = {0.f, 0.f, 0.f, 0.f, 0.f, 0.f};
    int c0 = chunk * 32;
    for (int c = c0; c < c0 + 32; ++c) {
        const float* xc = x + ((size_t)(b * CH + c) << 12);
        float xv[9];
        #pragma unroll
        for (int dy = 0; dy < 3; ++dy) {
            int yy = h + dy - 1;
            bool vy = (unsigned)yy < 64u;
            #pragma unroll
            for (int dx = 0; dx < 3; ++dx) {
                int xx = w + dx - 1;
                bool vv = vy && ((unsigned)xx < 64u);
                xv[dy * 3 + dx] = vv ? xc[yy * 64 + xx] : 0.f;
            }
        }
        const float* wb = w_off + (size_t)c * 9;
        #pragma unroll
        for (int s = 0; s < 6; ++s) {
            int chn = (s < 3) ? s * 6 : (s - 3) * 2 + 1;
            const float* wp = wb + (size_t)chn * (CH * 9);
            float a = acc[s];
            #pragma unroll
            for (int t = 0; t < 9; ++t) a = fmaf(xv[t], wp[t], a);
            acc[s] = a;
        }
    }
    float* po = partial + ((size_t)(chunk << 15) + m) * 6;
    #pragma unroll
    for (int s = 0; s < 6; ++s) po[s] = acc[s];
}

// ---------------- reorder w_main (O,C,3,3) f32 -> Wb[o][k*128+c] bf16 ----------------
__global__ __launch_bounds__(256) void wreorder_kernel(const float* __restrict__ w_main,
                                                       u16* __restrict__ Wb) {
    int idx = blockIdx.x * 256 + threadIdx.x;
    if (idx >= OO * KD) return;
    int o = idx / KD;
    int r = idx - o * KD;
    int k = r >> 7;
    int c = r & 127;
    Wb[idx] = f2bf(w_main[(size_t)o * KD + c * 9 + k]);
}

// ---------------- fused deformable-sample + GEMM ----------------
// One block = 64 pixels (one image row) x all 128 outputs. 4 waves.
// XCD-affinity swizzle: bid&7 selects the image, so each XCD's 64 blocks all
// gather from ONE 1 MB image slice of xt -> fully L2-resident per XCD.
// Double-buffered lA/lB: ONE barrier per K-step. Step k reads buf[k&1],
// step k+1 writes buf[(k+1)&1]; reads of buf[(k+1)&1] from step k-1 completed
// before barrier(k) (lgkmcnt precedes mfma), so write-after-read is safe.
__global__ __launch_bounds__(256) void fused_gemm_kernel(const __hip_bfloat16* __restrict__ xt,
                                                         const float* __restrict__ partial,
                                                         const float* __restrict__ b_off,
                                                         const u16* __restrict__ Wb,
                                                         const float* __restrict__ b_main,
                                                         float* __restrict__ out) {
    __shared__ float offs[64][6];
    __shared__ __align__(16) float4v twt[64][9];   // bilinear weights per (pix, tap)
    __shared__ __align__(16) int4 tbs[64][9];      // corner base offsets (u32-pair units)
    __shared__ __align__(16) u16 lA[2][128 * 32];  // weight tile dbuf
    __shared__ __align__(16) u16 lB[2][64 * 32];   // sample tile dbuf

    int tid = threadIdx.x;
    int orig = blockIdx.x;
    int b = orig & 7;                 // image == XCD
    int h = orig >> 3;                // row within image
    int m0 = ((b << 6) + h) << 6;     // first pixel index

    // -- prologue 1: gather offsets (6 per pixel) --
    for (int idx = tid; idx < 64 * 6; idx += 256) {
        int pix = idx / 6, s = idx % 6;
        int m = m0 + pix;
        int chn = (s < 3) ? s * 6 : (s - 3) * 2 + 1;
        float v = b_off[chn];
        #pragma unroll
        for (int q = 0; q < 4; ++q) v += partial[((size_t)(q << 15) + m) * 6 + s];
        offs[pix][s] = v;
    }
    __syncthreads();

    // -- prologue 2: per-(pix,tap) bilinear weights + corner bases --
    for (int idx = tid; idx < 64 * 9; idx += 256) {
        int pix = idx / 9, k = idx % 9;
        int i = k / 3, j = k - i * 3;
        float ox = offs[pix][0];
        if (i >= 1) ox += offs[pix][1];
        if (i >= 2) ox += offs[pix][2];
        float oy = offs[pix][3];
        if (j >= 1) oy += offs[pix][4];
        if (j >= 2) oy += offs[pix][5];
        const float step = 2.0f / 63.0f;
        float bxn = -1.0f + pix * step;
        float byn = -1.0f + h * step;
        float gx = fmaf(bxn + ox, 32.0f, 31.5f);
        float gy = fmaf(byn + oy, 32.0f, 31.5f);
        float x0f = floorf(gx), y0f = floorf(gy);
        float wx = gx - x0f, wy = gy - y0f;
        int ix0 = (int)x0f, iy0 = (int)y0f;
        int ix1 = ix0 + 1, iy1 = iy0 + 1;
        float fx0 = ((unsigned)ix0 < 64u) ? 1.f : 0.f;
        float fx1 = ((unsigned)ix1 < 64u) ? 1.f : 0.f;
        float fy0 = ((unsigned)iy0 < 64u) ? 1.f : 0.f;
        float fy1 = ((unsigned)iy1 < 64u) ? 1.f : 0.f;
        float4v wv;
        wv[0] = (1.f - wy) * (1.f - wx) * fy0 * fx0;
        wv[1] = (1.f - wy) * wx * fy0 * fx1;
        wv[2] = wy * (1.f - wx) * fy1 * fx0;
        wv[3] = wy * wx * fy1 * fx1;
        int cx0 = min(max(ix0, 0), 63), cx1 = min(max(ix1, 0), 63);
        int cy0 = min(max(iy0, 0), 63), cy1 = min(max(iy1, 0), 63);
        twt[pix][k] = wv;
        tbs[pix][k] = make_int4((cy0 * 64 + cx0) * 64, (cy0 * 64 + cx1) * 64,
                                (cy1 * 64 + cx0) * 64, (cy1 * 64 + cx1) * 64);
    }
    __syncthreads();

    // -- main loop setup --
    int wave = tid >> 6, lane = tid & 63;
    int wo = wave & 1;                // o half (64 rows each)
    int wp = wave >> 1;               // pixel half (32 each)
    int mrow = lane & 15;
    int q8 = (lane >> 4) * 8;

    int pix = tid >> 2;               // 0..63: sample-staging pixel
    int cg = (tid & 3) * 8;           // channel-group base within 32-col step
    const u32* xb = (const u32*)(xt + (((size_t)b << 12) * (size_t)CH));  // bf16 pairs
    const u16* abase = Wb + (size_t)(tid >> 2) * KD + (tid & 3) * 8;      // A staging
    int asto = (tid >> 2) * 32 + (tid & 3) * 8;                           // lA dest (u16)
    int bsto = pix * 32 + cg;

    float4v acc[4][2];
    #pragma unroll
    for (int sm = 0; sm < 4; ++sm)
        #pragma unroll
        for (int sn = 0; sn < 2; ++sn)
            acc[sm][sn] = (float4v){0.f, 0.f, 0.f, 0.f};

    float4v wv;
    int4 bv;
    uint4 u00, u01, u10, u11, a0, a1;

    auto issue = [&](int kk) {
        if ((kk & 3) == 0) {
            int k = kk >> 2;
            wv = twt[pix][k];
            bv = tbs[pix][k];
        }
        const u32* xc = xb + ((((kk & 3) << 5) + cg) >> 1);
        u00 = *(const uint4*)(xc + bv.x);
        u01 = *(const uint4*)(xc + bv.y);
        u10 = *(const uint4*)(xc + bv.z);
        u11 = *(const uint4*)(xc + bv.w);
        const u16* ap = abase + kk * 32;
        a0 = *(const uint4*)ap;
        a1 = *(const uint4*)(ap + (size_t)64 * KD);
    };

    issue(0);

    for (int kk = 0; kk < 36; ++kk) {
        int cur = kk & 1;
        u16* lAc = &lA[cur][0];
        u16* lBc = &lB[cur][0];

        // write phase: regs (loaded for step kk) -> LDS buf[cur]
        *(uint4*)&lAc[asto] = a0;
        *(uint4*)&lAc[asto + 64 * 32] = a1;
        {
            const u32* p00 = (const u32*)&u00;
            const u32* p01 = (const u32*)&u01;
            const u32* p10 = (const u32*)&u10;
            const u32* p11 = (const u32*)&u11;
            u32 outp[4];
            #pragma unroll
            for (int q = 0; q < 4; ++q) {
                float2v p = unpk(p00[q]) * wv[0];
                p += unpk(p01[q]) * wv[1];
                p += unpk(p10[q]) * wv[2];
                p += unpk(p11[q]) * wv[3];
                outp[q] = pack_bf16(p.x, p.y);
            }
            *(uint4*)&lBc[bsto] = *(const uint4*)outp;
        }

        if (kk < 35) issue(kk + 1);   // next step's gathers fly across barrier+mfma

        __syncthreads();              // the ONLY barrier per step

        short8 af[4], bfv[2];
        #pragma unroll
        for (int s = 0; s < 4; ++s)
            af[s] = *(const short8*)&lAc[(wo * 64 + s * 16 + mrow) * 32 + q8];
        #pragma unroll
        for (int s = 0; s < 2; ++s)
            bfv[s] = *(const short8*)&lBc[(wp * 32 + s * 16 + mrow) * 32 + q8];
        #pragma unroll
        for (int sm = 0; sm < 4; ++sm)
            #pragma unroll
            for (int sn = 0; sn < 2; ++sn)
                acc[sm][sn] = __builtin_amdgcn_mfma_f32_16x16x32_bf16(af[sm], bfv[sn],
                                                                     acc[sm][sn], 0, 0, 0);
    }

    // epilogue: C/D layout col=lane&15 (pixel), row=(lane>>4)*4+r (o)
    #pragma unroll
    for (int sm = 0; sm < 4; ++sm) {
        int o = wo * 64 + sm * 16 + (lane >> 4) * 4;
        #pragma unroll
        for (int sn = 0; sn < 2; ++sn) {
            int pcol = m0 + wp * 32 + sn * 16 + mrow;
            int rem = pcol & 4095;
            float* op = out + (((size_t)b * OO) << 12) + rem;
            #pragma unroll
            for (int r = 0; r < 4; ++r)
                op[(size_t)(o + r) << 12] = acc[sm][sn][r] + b_main[o + r];
        }
    }
}

extern "C" void kernel_launch(void* const* d_in, const int* in_sizes, int n_in,
                              void* d_out, int out_size, void* d_ws, size_t ws_size,
                              hipStream_t stream) {
    const float* x      = (const float*)d_in[0];
    const float* w_off  = (const float*)d_in[1];
    const float* b_off  = (const float*)d_in[2];
    const float* w_main = (const float*)d_in[3];
    const float* b_main = (const float*)d_in[4];
    float* out = (float*)d_out;

    char* ws = (char*)d_ws;
    __hip_bfloat16* xt = (__hip_bfloat16*)ws;                         // 8 MB
    float* partial = (float*)(ws + 8388608);                          // 3 MB
    u16* Wb   = (u16*)(ws + 8388608 + 3145728);                       // 288 KB

    transpose_kernel<<<512, 256, 0, stream>>>(x, xt);
    offset_conv_kernel<<<dim3(128, 4), 256, 0, stream>>>(x, w_off, partial);
    wreorder_kernel<<<576, 256, 0, stream>>>(w_main, Wb);
    fused_gemm_kernel<<<MPIX / 64, 256, 0, stream>>>(xt, partial, b_off, Wb, b_main, out);
}

// Round 3
// 129.348 us; speedup vs baseline: 1.0974x; 1.0423x over previous
//
#include <hip/hip_runtime.h>
#include <hip/hip_bf16.h>
#include <stdint.h>

typedef unsigned short u16;
typedef unsigned int u32;
typedef __attribute__((ext_vector_type(8))) short short8;
typedef __attribute__((ext_vector_type(4))) float float4v;
typedef __attribute__((ext_vector_type(2))) float float2v;

#define CH 128
#define OO 128
#define KD 1152      // 9*128
#define MPIX 32768   // 8*64*64

__device__ __forceinline__ u16 f2bf(float v) {
    __hip_bfloat16 h = __float2bfloat16(v);
    return *reinterpret_cast<u16*>(&h);
}

__device__ __forceinline__ float bf_lo(u32 u) {      // low bf16 of pair -> f32 (exact)
    u32 t = u << 16;
    return __builtin_bit_cast(float, t);
}
__device__ __forceinline__ float bf_hi(u32 u) {      // high bf16 of pair -> f32 (exact)
    u32 t = u & 0xffff0000u;
    return __builtin_bit_cast(float, t);
}
__device__ __forceinline__ float2v unpk(u32 u) {
    float2v r;
    r.x = bf_lo(u);
    r.y = bf_hi(u);
    return r;
}
__device__ __forceinline__ u32 pack_bf16(float lo, float hi) {  // round-to-nearest (ties away)
    u32 ul = __builtin_bit_cast(u32, lo);
    u32 uh = __builtin_bit_cast(u32, hi);
    return ((ul + 0x8000u) >> 16) | ((uh + 0x8000u) & 0xffff0000u);
}

// ---------------- merged prep: transpose + offset_conv + wreorder ----------------
// blocks [0,512):    transpose x (B,C,H,W) f32 -> xt (B,H,W,C) bf16
// blocks [512,1024): offset conv (6 needed channels, 4-way c-split)
// blocks [1024,1600): reorder w_main (O,C,3,3) f32 -> Wb[o][k*128+c] bf16
// All three are independent; branch is block-uniform.
__global__ __launch_bounds__(256) void prep_kernel(const float* __restrict__ x,
                                                   const float* __restrict__ w_off,
                                                   const float* __restrict__ w_main,
                                                   __hip_bfloat16* __restrict__ xt,
                                                   float* __restrict__ partial,
                                                   u16* __restrict__ Wb) {
    __shared__ float st[64][65];
    int tid = threadIdx.x;
    int bid = blockIdx.x;

    if (bid < 512) {
        // ---- transpose ----
        int bh = bid;                     // b*64 + h
        int b = bh >> 6;
        int h = bh & 63;
        const float* xb = x + ((size_t)b * CH) * 4096 + (size_t)h * 64;
        __hip_bfloat16* xo = xt + ((size_t)bh << 6) * CH;
        for (int cc0 = 0; cc0 < 128; cc0 += 64) {
            #pragma unroll
            for (int step = 0; step < 16; ++step) {
                int cl = (tid >> 6) + step * 4;
                int w = tid & 63;
                st[cl][w] = xb[(size_t)(cc0 + cl) * 4096 + w];
            }
            __syncthreads();
            #pragma unroll
            for (int step = 0; step < 16; ++step) {
                int w = (tid >> 6) + step * 4;
                int cl = tid & 63;
                xo[(size_t)w * CH + cc0 + cl] = __float2bfloat16(st[cl][w]);
            }
            __syncthreads();
        }
    } else if (bid < 1024) {
        // ---- offset conv ----
        int idx = bid - 512;
        int m = (idx & 127) * 256 + tid;
        int chunk = idx >> 7;             // 0..3, 32 channels each
        int b = m >> 12;
        int hw = m & 4095;
        int h = hw >> 6;
        int w = hw & 63;
        float acc[6] = {0.f, 0.f, 0.f, 0.f, 0.f, 0.f};
        int c0 = chunk * 32;
        for (int c = c0; c < c0 + 32; ++c) {
            const float* xc = x + ((size_t)(b * CH + c) << 12);
            float xv[9];
            #pragma unroll
            for (int dy = 0; dy < 3; ++dy) {
                int yy = h + dy - 1;
                bool vy = (unsigned)yy < 64u;
                #pragma unroll
                for (int dx = 0; dx < 3; ++dx) {
                    int xx = w + dx - 1;
                    bool vv = vy && ((unsigned)xx < 64u);
                    xv[dy * 3 + dx] = vv ? xc[yy * 64 + xx] : 0.f;
                }
            }
            const float* wb = w_off + (size_t)c * 9;
            #pragma unroll
            for (int s = 0; s < 6; ++s) {
                int chn = (s < 3) ? s * 6 : (s - 3) * 2 + 1;
                const float* wp = wb + (size_t)chn * (CH * 9);
                float a = acc[s];
                #pragma unroll
                for (int t = 0; t < 9; ++t) a = fmaf(xv[t], wp[t], a);
                acc[s] = a;
            }
        }
        float* po = partial + ((size_t)(chunk << 15) + m) * 6;
        #pragma unroll
        for (int s = 0; s < 6; ++s) po[s] = acc[s];
    } else {
        // ---- weight reorder ----
        int idx = (bid - 1024) * 256 + tid;
        if (idx < OO * KD) {
            int o = idx / KD;
            int r = idx - o * KD;
            int k = r >> 7;
            int c = r & 127;
            Wb[idx] = f2bf(w_main[(size_t)o * KD + c * 9 + k]);
        }
    }
}

// ---------------- fused deformable-sample + GEMM ----------------
// One block = 64 pixels (one image row) x all 128 outputs. 4 waves.
// XCD-affinity swizzle: bid&7 selects the image, so each XCD's 64 blocks all
// gather from ONE 1 MB image slice of xt -> fully L2-resident per XCD.
// Double-buffered lA/lB: ONE barrier per K-step. Step k reads buf[k&1],
// step k+1 writes buf[(k+1)&1]; reads of buf[(k+1)&1] from step k-1 completed
// before barrier(k) (lgkmcnt precedes mfma), so write-after-read is safe.
__global__ __launch_bounds__(256) void fused_gemm_kernel(const __hip_bfloat16* __restrict__ xt,
                                                         const float* __restrict__ partial,
                                                         const float* __restrict__ b_off,
                                                         const u16* __restrict__ Wb,
                                                         const float* __restrict__ b_main,
                                                         float* __restrict__ out) {
    __shared__ float offs[64][6];
    __shared__ __align__(16) float4v twt[64][9];   // bilinear weights per (pix, tap)
    __shared__ __align__(16) int4 tbs[64][9];      // corner base offsets (u32-pair units)
    __shared__ __align__(16) u16 lA[2][128 * 32];  // weight tile dbuf
    __shared__ __align__(16) u16 lB[2][64 * 32];   // sample tile dbuf

    int tid = threadIdx.x;
    int orig = blockIdx.x;
    int b = orig & 7;                 // image == XCD
    int h = orig >> 3;                // row within image
    int m0 = ((b << 6) + h) << 6;     // first pixel index

    // -- prologue 1: gather offsets (6 per pixel) --
    for (int idx = tid; idx < 64 * 6; idx += 256) {
        int pix = idx / 6, s = idx % 6;
        int m = m0 + pix;
        int chn = (s < 3) ? s * 6 : (s - 3) * 2 + 1;
        float v = b_off[chn];
        #pragma unroll
        for (int q = 0; q < 4; ++q) v += partial[((size_t)(q << 15) + m) * 6 + s];
        offs[pix][s] = v;
    }
    __syncthreads();

    // -- prologue 2: per-(pix,tap) bilinear weights + corner bases --
    for (int idx = tid; idx < 64 * 9; idx += 256) {
        int pix = idx / 9, k = idx % 9;
        int i = k / 3, j = k - i * 3;
        float ox = offs[pix][0];
        if (i >= 1) ox += offs[pix][1];
        if (i >= 2) ox += offs[pix][2];
        float oy = offs[pix][3];
        if (j >= 1) oy += offs[pix][4];
        if (j >= 2) oy += offs[pix][5];
        const float step = 2.0f / 63.0f;
        float bxn = -1.0f + pix * step;
        float byn = -1.0f + h * step;
        float gx = fmaf(bxn + ox, 32.0f, 31.5f);
        float gy = fmaf(byn + oy, 32.0f, 31.5f);
        float x0f = floorf(gx), y0f = floorf(gy);
        float wx = gx - x0f, wy = gy - y0f;
        int ix0 = (int)x0f, iy0 = (int)y0f;
        int ix1 = ix0 + 1, iy1 = iy0 + 1;
        float fx0 = ((unsigned)ix0 < 64u) ? 1.f : 0.f;
        float fx1 = ((unsigned)ix1 < 64u) ? 1.f : 0.f;
        float fy0 = ((unsigned)iy0 < 64u) ? 1.f : 0.f;
        float fy1 = ((unsigned)iy1 < 64u) ? 1.f : 0.f;
        float4v wv;
        wv[0] = (1.f - wy) * (1.f - wx) * fy0 * fx0;
        wv[1] = (1.f - wy) * wx * fy0 * fx1;
        wv[2] = wy * (1.f - wx) * fy1 * fx0;
        wv[3] = wy * wx * fy1 * fx1;
        int cx0 = min(max(ix0, 0), 63), cx1 = min(max(ix1, 0), 63);
        int cy0 = min(max(iy0, 0), 63), cy1 = min(max(iy1, 0), 63);
        twt[pix][k] = wv;
        tbs[pix][k] = make_int4((cy0 * 64 + cx0) * 64, (cy0 * 64 + cx1) * 64,
                                (cy1 * 64 + cx0) * 64, (cy1 * 64 + cx1) * 64);
    }
    __syncthreads();

    // -- main loop setup --
    int wave = tid >> 6, lane = tid & 63;
    int wo = wave & 1;                // o half (64 rows each)
    int wp = wave >> 1;               // pixel half (32 each)
    int mrow = lane & 15;
    int q8 = (lane >> 4) * 8;

    int pix = tid >> 2;               // 0..63: sample-staging pixel
    int cg = (tid & 3) * 8;           // channel-group base within 32-col step
    const u32* xb = (const u32*)(xt + (((size_t)b << 12) * (size_t)CH));  // bf16 pairs
    const u16* abase = Wb + (size_t)(tid >> 2) * KD + (tid & 3) * 8;      // A staging
    int asto = (tid >> 2) * 32 + (tid & 3) * 8;                           // lA dest (u16)
    int bsto = pix * 32 + cg;

    float4v acc[4][2];
    #pragma unroll
    for (int sm = 0; sm < 4; ++sm)
        #pragma unroll
        for (int sn = 0; sn < 2; ++sn)
            acc[sm][sn] = (float4v){0.f, 0.f, 0.f, 0.f};

    float4v wv;
    int4 bv;
    uint4 u00, u01, u10, u11, a0, a1;

    auto issue = [&](int kk) {
        if ((kk & 3) == 0) {
            int k = kk >> 2;
            wv = twt[pix][k];
            bv = tbs[pix][k];
        }
        const u32* xc = xb + ((((kk & 3) << 5) + cg) >> 1);
        u00 = *(const uint4*)(xc + bv.x);
        u01 = *(const uint4*)(xc + bv.y);
        u10 = *(const uint4*)(xc + bv.z);
        u11 = *(const uint4*)(xc + bv.w);
        const u16* ap = abase + kk * 32;
        a0 = *(const uint4*)ap;
        a1 = *(const uint4*)(ap + (size_t)64 * KD);
    };

    issue(0);

    for (int kk = 0; kk < 36; ++kk) {
        int cur = kk & 1;
        u16* lAc = &lA[cur][0];
        u16* lBc = &lB[cur][0];

        // write phase: regs (loaded for step kk) -> LDS buf[cur]
        *(uint4*)&lAc[asto] = a0;
        *(uint4*)&lAc[asto + 64 * 32] = a1;
        {
            const u32* p00 = (const u32*)&u00;
            const u32* p01 = (const u32*)&u01;
            const u32* p10 = (const u32*)&u10;
            const u32* p11 = (const u32*)&u11;
            u32 outp[4];
            #pragma unroll
            for (int q = 0; q < 4; ++q) {
                float2v p = unpk(p00[q]) * wv[0];
                p += unpk(p01[q]) * wv[1];
                p += unpk(p10[q]) * wv[2];
                p += unpk(p11[q]) * wv[3];
                outp[q] = pack_bf16(p.x, p.y);
            }
            *(uint4*)&lBc[bsto] = *(const uint4*)outp;
        }

        if (kk < 35) issue(kk + 1);   // next step's gathers fly across barrier+mfma

        __syncthreads();              // the ONLY barrier per step

        short8 af[4], bfv[2];
        #pragma unroll
        for (int s = 0; s < 4; ++s)
            af[s] = *(const short8*)&lAc[(wo * 64 + s * 16 + mrow) * 32 + q8];
        #pragma unroll
        for (int s = 0; s < 2; ++s)
            bfv[s] = *(const short8*)&lBc[(wp * 32 + s * 16 + mrow) * 32 + q8];
        #pragma unroll
        for (int sm = 0; sm < 4; ++sm)
            #pragma unroll
            for (int sn = 0; sn < 2; ++sn)
                acc[sm][sn] = __builtin_amdgcn_mfma_f32_16x16x32_bf16(af[sm], bfv[sn],
                                                                     acc[sm][sn], 0, 0, 0);
    }

    // epilogue: C/D layout col=lane&15 (pixel), row=(lane>>4)*4+r (o)
    #pragma unroll
    for (int sm = 0; sm < 4; ++sm) {
        int o = wo * 64 + sm * 16 + (lane >> 4) * 4;
        #pragma unroll
        for (int sn = 0; sn < 2; ++sn) {
            int pcol = m0 + wp * 32 + sn * 16 + mrow;
            int rem = pcol & 4095;
            float* op = out + (((size_t)b * OO) << 12) + rem;
            #pragma unroll
            for (int r = 0; r < 4; ++r)
                op[(size_t)(o + r) << 12] = acc[sm][sn][r] + b_main[o + r];
        }
    }
}

extern "C" void kernel_launch(void* const* d_in, const int* in_sizes, int n_in,
                              void* d_out, int out_size, void* d_ws, size_t ws_size,
                              hipStream_t stream) {
    const float* x      = (const float*)d_in[0];
    const float* w_off  = (const float*)d_in[1];
    const float* b_off  = (const float*)d_in[2];
    const float* w_main = (const float*)d_in[3];
    const float* b_main = (const float*)d_in[4];
    float* out = (float*)d_out;

    char* ws = (char*)d_ws;
    __hip_bfloat16* xt = (__hip_bfloat16*)ws;                         // 8 MB
    float* partial = (float*)(ws + 8388608);                          // 3 MB
    u16* Wb   = (u16*)(ws + 8388608 + 3145728);                       // 288 KB

    prep_kernel<<<1600, 256, 0, stream>>>(x, w_off, w_main, xt, partial, Wb);
    fused_gemm_kernel<<<MPIX / 64, 256, 0, stream>>>(xt, partial, b_off, Wb, b_main, out);
}